// Round 1
// baseline (1871.771 us; speedup 1.0000x reference)
//
#include <hip/hip_runtime.h>
#include <hip/hip_bf16.h>

#define NE 32
#define TOPK 4
#define HID 2048
#define INTER 768
#define NT 2048

typedef float f32x4 __attribute__((ext_vector_type(4)));
typedef unsigned int u32x4 __attribute__((ext_vector_type(4)));
typedef unsigned int u32x2 __attribute__((ext_vector_type(2)));
typedef short short8 __attribute__((ext_vector_type(8)));
typedef __bf16 bf16x8 __attribute__((ext_vector_type(8)));

__device__ inline unsigned short f2bf(float f) {
  unsigned u = __builtin_bit_cast(unsigned, f);
  u += 0x7fffu + ((u >> 16) & 1u);
  return (unsigned short)(u >> 16);
}
__device__ inline unsigned pack2(unsigned short a, unsigned short b) {
  return (unsigned)a | ((unsigned)b << 16);
}
__device__ inline f32x4 mfma_bf16(short8 a, short8 b, f32x4 c) {
  return __builtin_amdgcn_mfma_f32_16x16x32_bf16(
      __builtin_bit_cast(bf16x8, a), __builtin_bit_cast(bf16x8, b), c, 0, 0, 0);
}
// swizzled LDS index (ushort units), tiles are [row][64k], 16B-slot XOR swizzle
__device__ inline int swz(int row, int k) { return row * 64 + (k ^ ((row & 7) << 3)); }

// ---------------- router: 1 wave per token ----------------
__global__ __launch_bounds__(64) void k_router(const float* __restrict__ X,
                                               const float* __restrict__ Wg,
                                               int* __restrict__ expert_of,
                                               float* __restrict__ weight_of,
                                               int* __restrict__ counts) {
  const int n = blockIdx.x;
  const int lane = threadIdx.x;
  const float* x = X + (size_t)n * HID;
  float acc[NE];
#pragma unroll
  for (int e = 0; e < NE; ++e) acc[e] = 0.f;
  for (int h = lane; h < HID; h += 64) {
    const float xv = x[h];
    const f32x4* wr = (const f32x4*)(Wg + (size_t)h * NE);
#pragma unroll
    for (int q = 0; q < NE / 4; ++q) {
      f32x4 w4 = wr[q];
      acc[q * 4 + 0] += xv * w4[0];
      acc[q * 4 + 1] += xv * w4[1];
      acc[q * 4 + 2] += xv * w4[2];
      acc[q * 4 + 3] += xv * w4[3];
    }
  }
#pragma unroll
  for (int off = 32; off >= 1; off >>= 1) {
#pragma unroll
    for (int e = 0; e < NE; ++e) acc[e] += __shfl_xor(acc[e], off, 64);
  }
  if (lane == 0) {
    float m = acc[0];
#pragma unroll
    for (int e = 1; e < NE; ++e) m = fmaxf(m, acc[e]);
    unsigned used = 0;
    int idx[TOPK];
    float wv[TOPK];
    float wsum = 0.f;
    for (int k = 0; k < TOPK; ++k) {
      int best = 0;
      float bv = -1e30f;
      for (int e = 0; e < NE; ++e) {
        if (!((used >> e) & 1u) && acc[e] > bv) { bv = acc[e]; best = e; }
      }
      used |= 1u << best;
      float w = expf(bv - m);
      idx[k] = best;
      wv[k] = w;
      wsum += w;
    }
    const float inv = 1.f / wsum;
    for (int k = 0; k < TOPK; ++k) {
      expert_of[n * TOPK + k] = idx[k];
      weight_of[n * TOPK + k] = wv[k] * inv;
      atomicAdd(&counts[idx[k]], 1);
    }
  }
}

// ---------------- exclusive scan over 32 counts ----------------
__global__ void k_scan(const int* __restrict__ counts, int* __restrict__ offsets) {
  int s = 0;
  for (int e = 0; e < NE; ++e) { offsets[e] = s; s += counts[e]; }
  offsets[NE] = s;
}

// ---------------- deterministic stable scatter (1 wave per expert) ----------------
__global__ __launch_bounds__(64) void k_scatter(const int* __restrict__ expert_of,
                                                const float* __restrict__ weight_of,
                                                const int* __restrict__ offsets,
                                                int* __restrict__ slot_token,
                                                float* __restrict__ slot_w) {
  const int e = blockIdx.x;
  const int lane = threadIdx.x;
  int cnt = offsets[e];
  for (int a0 = 0; a0 < NT * TOPK; a0 += 64) {
    const int a = a0 + lane;
    const bool m = (expert_of[a] == e);
    const unsigned long long bal = __ballot(m);
    if (m) {
      const int pos = cnt + __popcll(bal & ((1ull << lane) - 1ull));
      slot_token[pos] = a >> 2;
      slot_w[pos] = weight_of[a];
    }
    cnt += __popcll(bal);
  }
}

// ---------------- X f32 -> bf16 ----------------
__global__ __launch_bounds__(256) void k_xconv(const float* __restrict__ X,
                                               unsigned short* __restrict__ Xb) {
  const int i = blockIdx.x * 256 + threadIdx.x;  // one float4 per thread
  const f32x4 v = ((const f32x4*)X)[i];
  u32x2 t = {pack2(f2bf(v[0]), f2bf(v[1])), pack2(f2bf(v[2]), f2bf(v[3]))};
  ((u32x2*)Xb)[i] = t;
}

// ---------------- GEMM1: X[sel] @ Wgu -> silu(g)*u*w -> Y (bf16) ----------------
__global__ __launch_bounds__(256) void k_gemm1(const unsigned short* __restrict__ Xb,
                                               const float* __restrict__ Wgu,
                                               const int* __restrict__ slot_token,
                                               const float* __restrict__ slot_w,
                                               const int* __restrict__ offsets,
                                               unsigned short* __restrict__ Y) {
  const int e = blockIdx.z;
  const int base = offsets[e];
  const int ne = offsets[e + 1] - base;
  const int m0 = blockIdx.x * 64;
  if (m0 >= ne) return;
  const int n0 = blockIdx.y * 64;  // in [0, INTER)
  const int tid = threadIdx.x;
  const int lane = tid & 63, wv = tid >> 6;
  const int wr = wv >> 1, wc = wv & 1;

  __shared__ __attribute__((aligned(16))) unsigned short As[64 * 64];
  __shared__ __attribute__((aligned(16))) unsigned short Bg[64 * 64];
  __shared__ __attribute__((aligned(16))) unsigned short Bu[64 * 64];

  f32x4 accg[2][2], accu[2][2];
#pragma unroll
  for (int i = 0; i < 2; ++i)
#pragma unroll
    for (int j = 0; j < 2; ++j) {
      f32x4 z = {0.f, 0.f, 0.f, 0.f};
      accg[i][j] = z;
      accu[i][j] = z;
    }

  // A staging: fixed rows per thread
  const int arow0 = tid >> 3;  // 0..31
  const int akb = tid & 7;
  const int arow1 = arow0 + 32;
  const int tok0 = slot_token[base + min(m0 + arow0, ne - 1)];
  const int tok1 = slot_token[base + min(m0 + arow1, ne - 1)];
  const unsigned short* ap0 = Xb + (size_t)tok0 * HID + akb * 8;
  const unsigned short* ap1 = Xb + (size_t)tok1 * HID + akb * 8;
  const int ad0 = swz(arow0, akb * 8);
  const int ad1 = swz(arow1, akb * 8);

  // B staging coords
  const int kq = tid >> 4, nq = tid & 15;
  const float* bp0 = Wgu + (size_t)e * HID * (2 * INTER) + (size_t)(kq * 4) * (2 * INTER) +
                     n0 + nq * 4;

  const int fr = lane & 15, fo = lane >> 4;

  for (int k0 = 0; k0 < HID; k0 += 64) {
    *(u32x4*)&As[ad0] = *(const u32x4*)(ap0 + k0);
    *(u32x4*)&As[ad1] = *(const u32x4*)(ap1 + k0);
    const float* bp = bp0 + (size_t)k0 * (2 * INTER);
    f32x4 g[4], u[4];
#pragma unroll
    for (int kk = 0; kk < 4; ++kk) {
      g[kk] = *(const f32x4*)(bp + (size_t)kk * (2 * INTER));
      u[kk] = *(const f32x4*)(bp + (size_t)kk * (2 * INTER) + INTER);
    }
#pragma unroll
    for (int ni = 0; ni < 4; ++ni) {
      const int n = nq * 4 + ni;
      const int di = swz(n, kq * 4);
      u32x2 tg = {pack2(f2bf(g[0][ni]), f2bf(g[1][ni])),
                  pack2(f2bf(g[2][ni]), f2bf(g[3][ni]))};
      u32x2 tu = {pack2(f2bf(u[0][ni]), f2bf(u[1][ni])),
                  pack2(f2bf(u[2][ni]), f2bf(u[3][ni]))};
      *(u32x2*)&Bg[di] = tg;
      *(u32x2*)&Bu[di] = tu;
    }
    __syncthreads();
#pragma unroll
    for (int ki = 0; ki < 2; ++ki) {
      const int kk = ki * 32 + fo * 8;
      short8 a0 = *(const short8*)&As[swz(wr * 32 + fr, kk)];
      short8 a1 = *(const short8*)&As[swz(wr * 32 + 16 + fr, kk)];
      short8 b0g = *(const short8*)&Bg[swz(wc * 32 + fr, kk)];
      short8 b1g = *(const short8*)&Bg[swz(wc * 32 + 16 + fr, kk)];
      short8 b0u = *(const short8*)&Bu[swz(wc * 32 + fr, kk)];
      short8 b1u = *(const short8*)&Bu[swz(wc * 32 + 16 + fr, kk)];
      accg[0][0] = mfma_bf16(a0, b0g, accg[0][0]);
      accg[0][1] = mfma_bf16(a0, b1g, accg[0][1]);
      accg[1][0] = mfma_bf16(a1, b0g, accg[1][0]);
      accg[1][1] = mfma_bf16(a1, b1g, accg[1][1]);
      accu[0][0] = mfma_bf16(a0, b0u, accu[0][0]);
      accu[0][1] = mfma_bf16(a0, b1u, accu[0][1]);
      accu[1][0] = mfma_bf16(a1, b0u, accu[1][0]);
      accu[1][1] = mfma_bf16(a1, b1u, accu[1][1]);
    }
    __syncthreads();
  }
#pragma unroll
  for (int mi = 0; mi < 2; ++mi) {
#pragma unroll
    for (int j = 0; j < 4; ++j) {
      const int row = wr * 32 + mi * 16 + fo * 4 + j;
      const int gm = m0 + row;
      if (gm < ne) {
        const float wgt = slot_w[base + gm];
        unsigned short* yp = Y + (size_t)(base + gm) * INTER + n0 + wc * 32;
#pragma unroll
        for (int nj = 0; nj < 2; ++nj) {
          const float gvv = accg[mi][nj][j];
          const float uvv = accu[mi][nj][j];
          const float yv = (gvv / (1.0f + __expf(-gvv))) * uvv * wgt;
          yp[nj * 16 + fr] = f2bf(yv);
        }
      }
    }
  }
}

// ---------------- GEMM2: Y @ Wd -> atomic scatter into out ----------------
__global__ __launch_bounds__(256) void k_gemm2(const unsigned short* __restrict__ Y,
                                               const float* __restrict__ Wd,
                                               const int* __restrict__ slot_token,
                                               const int* __restrict__ offsets,
                                               float* __restrict__ out) {
  const int e = blockIdx.z;
  const int base = offsets[e];
  const int ne = offsets[e + 1] - base;
  const int m0 = blockIdx.x * 64;
  if (m0 >= ne) return;
  const int n0 = blockIdx.y * 64;  // in [0, HID)
  const int tid = threadIdx.x;
  const int lane = tid & 63, wv = tid >> 6;
  const int wr = wv >> 1, wc = wv & 1;

  __shared__ __attribute__((aligned(16))) unsigned short As[64 * 64];
  __shared__ __attribute__((aligned(16))) unsigned short Bs[64 * 64];

  f32x4 acc[2][2];
#pragma unroll
  for (int i = 0; i < 2; ++i)
#pragma unroll
    for (int j = 0; j < 2; ++j) {
      f32x4 z = {0.f, 0.f, 0.f, 0.f};
      acc[i][j] = z;
    }

  const int arow0 = tid >> 3;
  const int akb = tid & 7;
  const int arow1 = arow0 + 32;
  const unsigned short* ap0 =
      Y + (size_t)(base + min(m0 + arow0, ne - 1)) * INTER + akb * 8;
  const unsigned short* ap1 =
      Y + (size_t)(base + min(m0 + arow1, ne - 1)) * INTER + akb * 8;
  const int ad0 = swz(arow0, akb * 8);
  const int ad1 = swz(arow1, akb * 8);

  const int kq = tid >> 4, nq = tid & 15;
  const float* bp0 = Wd + (size_t)e * INTER * HID + (size_t)(kq * 4) * HID + n0 + nq * 4;

  const int fr = lane & 15, fo = lane >> 4;

  for (int k0 = 0; k0 < INTER; k0 += 64) {
    *(u32x4*)&As[ad0] = *(const u32x4*)(ap0 + k0);
    *(u32x4*)&As[ad1] = *(const u32x4*)(ap1 + k0);
    const float* bp = bp0 + (size_t)k0 * HID;
    f32x4 g[4];
#pragma unroll
    for (int kk = 0; kk < 4; ++kk) g[kk] = *(const f32x4*)(bp + (size_t)kk * HID);
#pragma unroll
    for (int ni = 0; ni < 4; ++ni) {
      const int n = nq * 4 + ni;
      const int di = swz(n, kq * 4);
      u32x2 tb = {pack2(f2bf(g[0][ni]), f2bf(g[1][ni])),
                  pack2(f2bf(g[2][ni]), f2bf(g[3][ni]))};
      *(u32x2*)&Bs[di] = tb;
    }
    __syncthreads();
#pragma unroll
    for (int ki = 0; ki < 2; ++ki) {
      const int kk = ki * 32 + fo * 8;
      short8 a0 = *(const short8*)&As[swz(wr * 32 + fr, kk)];
      short8 a1 = *(const short8*)&As[swz(wr * 32 + 16 + fr, kk)];
      short8 b0 = *(const short8*)&Bs[swz(wc * 32 + fr, kk)];
      short8 b1 = *(const short8*)&Bs[swz(wc * 32 + 16 + fr, kk)];
      acc[0][0] = mfma_bf16(a0, b0, acc[0][0]);
      acc[0][1] = mfma_bf16(a0, b1, acc[0][1]);
      acc[1][0] = mfma_bf16(a1, b0, acc[1][0]);
      acc[1][1] = mfma_bf16(a1, b1, acc[1][1]);
    }
    __syncthreads();
  }
#pragma unroll
  for (int mi = 0; mi < 2; ++mi) {
#pragma unroll
    for (int j = 0; j < 4; ++j) {
      const int row = wr * 32 + mi * 16 + fo * 4 + j;
      const int gm = m0 + row;
      if (gm < ne) {
        const int tok = slot_token[base + gm];
        float* op = out + (size_t)tok * HID + n0 + wc * 32;
#pragma unroll
        for (int nj = 0; nj < 2; ++nj) {
          atomicAdd(&op[nj * 16 + fr], acc[mi][nj][j]);
        }
      }
    }
  }
}

extern "C" void kernel_launch(void* const* d_in, const int* in_sizes, int n_in,
                              void* d_out, int out_size, void* d_ws, size_t ws_size,
                              hipStream_t stream) {
  (void)in_sizes; (void)n_in; (void)ws_size;
  const float* X = (const float*)d_in[0];
  const float* Wg = (const float*)d_in[1];
  const float* Wgu = (const float*)d_in[2];
  const float* Wd = (const float*)d_in[3];
  float* out = (float*)d_out;

  char* ws = (char*)d_ws;
  int* counts = (int*)(ws + 0);              // 128 B
  int* offsets = (int*)(ws + 256);           // 33 ints
  int* expert_of = (int*)(ws + 1024);        // 8192 ints
  float* weight_of = (float*)(ws + 1024 + 32768);
  int* slot_token = (int*)(ws + 1024 + 2 * 32768);
  float* slot_w = (float*)(ws + 1024 + 3 * 32768);
  unsigned short* Xb = (unsigned short*)(ws + 132096);              // 8 MB
  unsigned short* Yb = (unsigned short*)(ws + 132096 + 8388608);    // 12 MB

  hipMemsetAsync(counts, 0, 128, stream);
  hipMemsetAsync(d_out, 0, (size_t)out_size * sizeof(float), stream);

  k_router<<<NT, 64, 0, stream>>>(X, Wg, expert_of, weight_of, counts);
  k_scan<<<1, 1, 0, stream>>>(counts, offsets);
  k_scatter<<<NE, 64, 0, stream>>>(expert_of, weight_of, offsets, slot_token, slot_w);
  k_xconv<<<(NT * HID / 4) / 256, 256, 0, stream>>>(X, Xb);
  k_gemm1<<<dim3(NT / 64, INTER / 64, NE), 256, 0, stream>>>(Xb, Wgu, slot_token, slot_w,
                                                             offsets, Yb);
  k_gemm2<<<dim3(NT / 64, HID / 64, NE), 256, 0, stream>>>(Yb, Wd, slot_token, offsets, out);
}

// Round 2
// 1280.303 us; speedup vs baseline: 1.4620x; 1.4620x over previous
//
#include <hip/hip_runtime.h>
#include <hip/hip_bf16.h>

#define NE 32
#define TOPK 4
#define HID 2048
#define INTER 768
#define NT 2048

typedef float f32x4 __attribute__((ext_vector_type(4)));
typedef unsigned int u32x4 __attribute__((ext_vector_type(4)));
typedef unsigned int u32x2 __attribute__((ext_vector_type(2)));
typedef short short8 __attribute__((ext_vector_type(8)));
typedef __bf16 bf16x8 __attribute__((ext_vector_type(8)));

__device__ inline unsigned short f2bf(float f) {
  unsigned u = __builtin_bit_cast(unsigned, f);
  u += 0x7fffu + ((u >> 16) & 1u);
  return (unsigned short)(u >> 16);
}
__device__ inline unsigned pack2(unsigned short a, unsigned short b) {
  return (unsigned)a | ((unsigned)b << 16);
}
__device__ inline f32x4 mfma_bf16(short8 a, short8 b, f32x4 c) {
  return __builtin_amdgcn_mfma_f32_16x16x32_bf16(
      __builtin_bit_cast(bf16x8, a), __builtin_bit_cast(bf16x8, b), c, 0, 0, 0);
}
__device__ inline void gload16(const void* g, void* l) {
  __builtin_amdgcn_global_load_lds(
      (const __attribute__((address_space(1))) void*)g,
      (__attribute__((address_space(3))) void*)l, 16, 0, 0);
}

// ---------------- router: 1 wave per token ----------------
__global__ __launch_bounds__(64) void k_router(const float* __restrict__ X,
                                               const float* __restrict__ Wg,
                                               int* __restrict__ expert_of,
                                               float* __restrict__ weight_of,
                                               int* __restrict__ counts) {
  const int n = blockIdx.x;
  const int lane = threadIdx.x;
  const float* x = X + (size_t)n * HID;
  float acc[NE];
#pragma unroll
  for (int e = 0; e < NE; ++e) acc[e] = 0.f;
  for (int h = lane; h < HID; h += 64) {
    const float xv = x[h];
    const f32x4* wr = (const f32x4*)(Wg + (size_t)h * NE);
#pragma unroll
    for (int q = 0; q < NE / 4; ++q) {
      f32x4 w4 = wr[q];
      acc[q * 4 + 0] += xv * w4[0];
      acc[q * 4 + 1] += xv * w4[1];
      acc[q * 4 + 2] += xv * w4[2];
      acc[q * 4 + 3] += xv * w4[3];
    }
  }
#pragma unroll
  for (int off = 32; off >= 1; off >>= 1) {
#pragma unroll
    for (int e = 0; e < NE; ++e) acc[e] += __shfl_xor(acc[e], off, 64);
  }
  if (lane == 0) {
    float m = acc[0];
#pragma unroll
    for (int e = 1; e < NE; ++e) m = fmaxf(m, acc[e]);
    unsigned used = 0;
    int idx[TOPK];
    float wv[TOPK];
    float wsum = 0.f;
    for (int k = 0; k < TOPK; ++k) {
      int best = 0;
      float bv = -1e30f;
      for (int e = 0; e < NE; ++e) {
        if (!((used >> e) & 1u) && acc[e] > bv) { bv = acc[e]; best = e; }
      }
      used |= 1u << best;
      float w = expf(bv - m);
      idx[k] = best;
      wv[k] = w;
      wsum += w;
    }
    const float inv = 1.f / wsum;
    for (int k = 0; k < TOPK; ++k) {
      expert_of[n * TOPK + k] = idx[k];
      weight_of[n * TOPK + k] = wv[k] * inv;
      atomicAdd(&counts[idx[k]], 1);
    }
  }
}

// ---------------- exclusive scan over 32 counts ----------------
__global__ void k_scan(const int* __restrict__ counts, int* __restrict__ offsets) {
  int s = 0;
  for (int e = 0; e < NE; ++e) { offsets[e] = s; s += counts[e]; }
  offsets[NE] = s;
}

// ---------------- deterministic stable scatter (1 wave per expert) ----------------
__global__ __launch_bounds__(64) void k_scatter(const int* __restrict__ expert_of,
                                                const float* __restrict__ weight_of,
                                                const int* __restrict__ offsets,
                                                int* __restrict__ slot_token,
                                                float* __restrict__ slot_w) {
  const int e = blockIdx.x;
  const int lane = threadIdx.x;
  int cnt = offsets[e];
  for (int a0 = 0; a0 < NT * TOPK; a0 += 64) {
    const int a = a0 + lane;
    const bool m = (expert_of[a] == e);
    const unsigned long long bal = __ballot(m);
    if (m) {
      const int pos = cnt + __popcll(bal & ((1ull << lane) - 1ull));
      slot_token[pos] = a >> 2;
      slot_w[pos] = weight_of[a];
    }
    cnt += __popcll(bal);
  }
}

// ---------------- X f32 -> bf16 ----------------
__global__ __launch_bounds__(256) void k_xconv(const float* __restrict__ X,
                                               unsigned short* __restrict__ Xb) {
  const int i = blockIdx.x * 256 + threadIdx.x;
  const f32x4 v = ((const f32x4*)X)[i];
  u32x2 t = {pack2(f2bf(v[0]), f2bf(v[1])), pack2(f2bf(v[2]), f2bf(v[3]))};
  ((u32x2*)Xb)[i] = t;
}

// ---------------- W f32 [E][K][N] -> bf16 [E][N][K] (transpose+convert) ----------------
__global__ __launch_bounds__(256) void k_wconv(const float* __restrict__ W,
                                               unsigned short* __restrict__ WT,
                                               int K, int N) {
  const int e = blockIdx.z;
  const int k0 = blockIdx.x * 64;
  const int n0 = blockIdx.y * 64;
  __shared__ float T[64][65];
  const float* src = W + ((size_t)e * K + k0) * N + n0;
  const int t = threadIdx.x;
#pragma unroll
  for (int p = 0; p < 4; ++p) {
    const int q = p * 256 + t;          // 0..1023 quads
    const int r = q >> 4, c4 = q & 15;  // 64 rows x 16 quads
    f32x4 v = *(const f32x4*)(src + (size_t)r * N + c4 * 4);
    T[r][c4 * 4 + 0] = v[0];
    T[r][c4 * 4 + 1] = v[1];
    T[r][c4 * 4 + 2] = v[2];
    T[r][c4 * 4 + 3] = v[3];
  }
  __syncthreads();
  unsigned short* dst = WT + ((size_t)e * N + n0) * K + k0;
#pragma unroll
  for (int p = 0; p < 2; ++p) {
    const int ch = p * 256 + t;          // 0..511 chunks (64 n-rows x 8 chunks)
    const int n = ch >> 3, kc = ch & 7;
    __attribute__((aligned(16))) unsigned short tmp[8];
#pragma unroll
    for (int j = 0; j < 8; ++j) tmp[j] = f2bf(T[kc * 8 + j][n]);
    *(u32x4*)(dst + (size_t)n * K + kc * 8) = *(const u32x4*)tmp;
  }
}

// ---------------- GEMM1: X[sel] @ WguT^T -> silu(g)*u*w -> Y (bf16) ----------------
// tile: 128m x 64n(gate, paired with up), BK=64, 4 waves (2x2), wave tile 64m x 32n
__global__ __launch_bounds__(256) void k_gemm1(const unsigned short* __restrict__ Xb,
                                               const unsigned short* __restrict__ WguT,
                                               const int* __restrict__ slot_token,
                                               const float* __restrict__ slot_w,
                                               const int* __restrict__ offsets,
                                               unsigned short* __restrict__ Y) {
  const int e = blockIdx.z;
  const int base = offsets[e];
  const int ne = offsets[e + 1] - base;
  const int m0 = blockIdx.x * 128;
  if (m0 >= ne) return;
  const int n0 = blockIdx.y * 64;
  const int tid = threadIdx.x;
  const int lane = tid & 63, w = tid >> 6;
  const int wr = w >> 1, wc = w & 1;
  const int fr = lane & 15, fo = lane >> 4;
  const int lr = lane >> 3, lk = lane & 7;

  __shared__ __attribute__((aligned(16))) unsigned short As[128 * 64];
  __shared__ __attribute__((aligned(16))) unsigned short Bg[64 * 64];
  __shared__ __attribute__((aligned(16))) unsigned short Bu[64 * 64];

  f32x4 accg[4][2], accu[4][2];
#pragma unroll
  for (int i = 0; i < 4; ++i)
#pragma unroll
    for (int j = 0; j < 2; ++j) {
      f32x4 z = {0.f, 0.f, 0.f, 0.f};
      accg[i][j] = z;
      accu[i][j] = z;
    }

  // per-lane global sources (pre-swizzled chunk so swizzled LDS read is correct)
  const unsigned short* asrc[4];
#pragma unroll
  for (int i = 0; i < 4; ++i) {
    const int ra = (w * 4 + i) * 8 + lr;  // 0..127
    const int tok = slot_token[base + min(m0 + ra, ne - 1)];
    asrc[i] = Xb + (size_t)tok * HID + ((lk ^ (ra & 7)) << 3);
  }
  const unsigned short* gsrc[2];
  const unsigned short* usrc[2];
#pragma unroll
  for (int j = 0; j < 2; ++j) {
    const int rb = (w * 2 + j) * 8 + lr;  // 0..63
    gsrc[j] = WguT + ((size_t)e * (2 * INTER) + n0 + rb) * HID + ((lk ^ (rb & 7)) << 3);
    usrc[j] = WguT + ((size_t)e * (2 * INTER) + INTER + n0 + rb) * HID + ((lk ^ (rb & 7)) << 3);
  }

  for (int k0 = 0; k0 < HID; k0 += 64) {
#pragma unroll
    for (int i = 0; i < 4; ++i) gload16(asrc[i] + k0, &As[(w * 4 + i) * 512]);
#pragma unroll
    for (int j = 0; j < 2; ++j) {
      gload16(gsrc[j] + k0, &Bg[(w * 2 + j) * 512]);
      gload16(usrc[j] + k0, &Bu[(w * 2 + j) * 512]);
    }
    __syncthreads();
#pragma unroll
    for (int ks = 0; ks < 2; ++ks) {
      const int c = ks * 4 + fo;
      short8 a[4], bg[2], bu[2];
#pragma unroll
      for (int mi = 0; mi < 4; ++mi) {
        const int row = wr * 64 + mi * 16 + fr;
        a[mi] = *(const short8*)&As[row * 64 + ((c ^ (row & 7)) << 3)];
      }
#pragma unroll
      for (int ni = 0; ni < 2; ++ni) {
        const int row = wc * 32 + ni * 16 + fr;
        const int off = row * 64 + ((c ^ (row & 7)) << 3);
        bg[ni] = *(const short8*)&Bg[off];
        bu[ni] = *(const short8*)&Bu[off];
      }
#pragma unroll
      for (int mi = 0; mi < 4; ++mi)
#pragma unroll
        for (int ni = 0; ni < 2; ++ni) {
          accg[mi][ni] = mfma_bf16(a[mi], bg[ni], accg[mi][ni]);
          accu[mi][ni] = mfma_bf16(a[mi], bu[ni], accu[mi][ni]);
        }
    }
    __syncthreads();
  }

#pragma unroll
  for (int mi = 0; mi < 4; ++mi) {
#pragma unroll
    for (int j = 0; j < 4; ++j) {
      const int gm = m0 + wr * 64 + mi * 16 + fo * 4 + j;
      if (gm < ne) {
        const float wgt = slot_w[base + gm];
        unsigned short* yp = Y + (size_t)(base + gm) * INTER + n0 + wc * 32;
#pragma unroll
        for (int ni = 0; ni < 2; ++ni) {
          const float g = accg[mi][ni][j];
          const float u = accu[mi][ni][j];
          const float yv = (g / (1.0f + __expf(-g))) * u * wgt;
          yp[ni * 16 + fr] = f2bf(yv);
        }
      }
    }
  }
}

// ---------------- GEMM2: Y @ WdT^T -> atomic scatter into out ----------------
// tile: 128m x 128n, BK=64, 4 waves (2x2), wave tile 64x64
__global__ __launch_bounds__(256) void k_gemm2(const unsigned short* __restrict__ Y,
                                               const unsigned short* __restrict__ WdT,
                                               const int* __restrict__ slot_token,
                                               const int* __restrict__ offsets,
                                               float* __restrict__ out) {
  const int e = blockIdx.z;
  const int base = offsets[e];
  const int ne = offsets[e + 1] - base;
  const int m0 = blockIdx.x * 128;
  if (m0 >= ne) return;
  const int n0 = blockIdx.y * 128;
  const int tid = threadIdx.x;
  const int lane = tid & 63, w = tid >> 6;
  const int wr = w >> 1, wc = w & 1;
  const int fr = lane & 15, fo = lane >> 4;
  const int lr = lane >> 3, lk = lane & 7;

  __shared__ __attribute__((aligned(16))) unsigned short As[128 * 64];
  __shared__ __attribute__((aligned(16))) unsigned short Bs[128 * 64];

  f32x4 acc[4][4];
#pragma unroll
  for (int i = 0; i < 4; ++i)
#pragma unroll
    for (int j = 0; j < 4; ++j) {
      f32x4 z = {0.f, 0.f, 0.f, 0.f};
      acc[i][j] = z;
    }

  const unsigned short* asrc[4];
  const unsigned short* bsrc[4];
#pragma unroll
  for (int i = 0; i < 4; ++i) {
    const int ra = (w * 4 + i) * 8 + lr;  // 0..127
    const int grow = base + min(m0 + ra, ne - 1);
    asrc[i] = Y + (size_t)grow * INTER + ((lk ^ (ra & 7)) << 3);
    bsrc[i] = WdT + ((size_t)e * HID + n0 + ra) * INTER + ((lk ^ (ra & 7)) << 3);
  }

  for (int k0 = 0; k0 < INTER; k0 += 64) {
#pragma unroll
    for (int i = 0; i < 4; ++i) {
      gload16(asrc[i] + k0, &As[(w * 4 + i) * 512]);
      gload16(bsrc[i] + k0, &Bs[(w * 4 + i) * 512]);
    }
    __syncthreads();
#pragma unroll
    for (int ks = 0; ks < 2; ++ks) {
      const int c = ks * 4 + fo;
      short8 a[4], b[4];
#pragma unroll
      for (int mi = 0; mi < 4; ++mi) {
        const int row = wr * 64 + mi * 16 + fr;
        a[mi] = *(const short8*)&As[row * 64 + ((c ^ (row & 7)) << 3)];
      }
#pragma unroll
      for (int ni = 0; ni < 4; ++ni) {
        const int row = wc * 64 + ni * 16 + fr;
        b[ni] = *(const short8*)&Bs[row * 64 + ((c ^ (row & 7)) << 3)];
      }
#pragma unroll
      for (int mi = 0; mi < 4; ++mi)
#pragma unroll
        for (int ni = 0; ni < 4; ++ni) acc[mi][ni] = mfma_bf16(a[mi], b[ni], acc[mi][ni]);
    }
    __syncthreads();
  }

#pragma unroll
  for (int mi = 0; mi < 4; ++mi) {
#pragma unroll
    for (int j = 0; j < 4; ++j) {
      const int gm = m0 + wr * 64 + mi * 16 + fo * 4 + j;
      if (gm < ne) {
        const int tok = slot_token[base + gm];
        float* op = out + (size_t)tok * HID + n0 + wc * 64;
#pragma unroll
        for (int ni = 0; ni < 4; ++ni) atomicAdd(&op[ni * 16 + fr], acc[mi][ni][j]);
      }
    }
  }
}

extern "C" void kernel_launch(void* const* d_in, const int* in_sizes, int n_in,
                              void* d_out, int out_size, void* d_ws, size_t ws_size,
                              hipStream_t stream) {
  (void)in_sizes; (void)n_in; (void)ws_size;
  const float* X = (const float*)d_in[0];
  const float* Wg = (const float*)d_in[1];
  const float* Wgu = (const float*)d_in[2];
  const float* Wd = (const float*)d_in[3];
  float* out = (float*)d_out;

  char* ws = (char*)d_ws;
  int* counts = (int*)(ws + 0);
  int* offsets = (int*)(ws + 256);
  int* expert_of = (int*)(ws + 1024);
  float* weight_of = (float*)(ws + 1024 + 32768);
  int* slot_token = (int*)(ws + 1024 + 2 * 32768);
  float* slot_w = (float*)(ws + 1024 + 3 * 32768);
  unsigned short* Xb = (unsigned short*)(ws + 132096);                    // 8 MB
  unsigned short* Yb = (unsigned short*)(ws + 8520704);                   // 12.6 MB
  unsigned short* WguT = (unsigned short*)(ws + 21103616);                // 201.3 MB
  unsigned short* WdT = (unsigned short*)(ws + 222430208);                // 100.7 MB

  hipMemsetAsync(counts, 0, 128, stream);
  hipMemsetAsync(d_out, 0, (size_t)out_size * sizeof(float), stream);

  k_router<<<NT, 64, 0, stream>>>(X, Wg, expert_of, weight_of, counts);
  k_scan<<<1, 1, 0, stream>>>(counts, offsets);
  k_scatter<<<NE, 64, 0, stream>>>(expert_of, weight_of, offsets, slot_token, slot_w);
  k_xconv<<<(NT * HID / 4) / 256, 256, 0, stream>>>(X, Xb);
  k_wconv<<<dim3(HID / 64, (2 * INTER) / 64, NE), 256, 0, stream>>>(Wgu, WguT, HID, 2 * INTER);
  k_wconv<<<dim3(INTER / 64, HID / 64, NE), 256, 0, stream>>>(Wd, WdT, INTER, HID);
  k_gemm1<<<dim3(16, INTER / 64, NE), 256, 0, stream>>>(Xb, WguT, slot_token, slot_w,
                                                        offsets, Yb);
  k_gemm2<<<dim3(16, HID / 128, NE), 256, 0, stream>>>(Yb, WdT, slot_token, offsets, out);
}

// Round 3
// 593.008 us; speedup vs baseline: 3.1564x; 2.1590x over previous
//
#include <hip/hip_runtime.h>
#include <hip/hip_bf16.h>

#define NE 32
#define TOPK 4
#define HID 2048
#define INTER 768
#define NT 2048
#define MAXTILE 96

typedef float f32x4 __attribute__((ext_vector_type(4)));
typedef unsigned int u32x4 __attribute__((ext_vector_type(4)));
typedef unsigned int u32x2 __attribute__((ext_vector_type(2)));
typedef short short8 __attribute__((ext_vector_type(8)));
typedef __bf16 bf16x8 __attribute__((ext_vector_type(8)));

__device__ inline unsigned short f2bf(float f) {
  unsigned u = __builtin_bit_cast(unsigned, f);
  u += 0x7fffu + ((u >> 16) & 1u);
  return (unsigned short)(u >> 16);
}
__device__ inline unsigned pack2(unsigned short a, unsigned short b) {
  return (unsigned)a | ((unsigned)b << 16);
}
__device__ inline f32x4 mfma_bf16(short8 a, short8 b, f32x4 c) {
  return __builtin_amdgcn_mfma_f32_16x16x32_bf16(
      __builtin_bit_cast(bf16x8, a), __builtin_bit_cast(bf16x8, b), c, 0, 0, 0);
}
__device__ inline void gload16(const void* g, void* l) {
  __builtin_amdgcn_global_load_lds(
      (const __attribute__((address_space(1))) void*)g,
      (__attribute__((address_space(3))) void*)l, 16, 0, 0);
}

// ---------------- router: 1 wave per token ----------------
__global__ __launch_bounds__(64) void k_router(const float* __restrict__ X,
                                               const float* __restrict__ Wg,
                                               int* __restrict__ expert_of,
                                               float* __restrict__ weight_of,
                                               int* __restrict__ counts) {
  const int n = blockIdx.x;
  const int lane = threadIdx.x;
  const float* x = X + (size_t)n * HID;
  float acc[NE];
#pragma unroll
  for (int e = 0; e < NE; ++e) acc[e] = 0.f;
  for (int h = lane; h < HID; h += 64) {
    const float xv = x[h];
    const f32x4* wr = (const f32x4*)(Wg + (size_t)h * NE);
#pragma unroll
    for (int q = 0; q < NE / 4; ++q) {
      f32x4 w4 = wr[q];
      acc[q * 4 + 0] += xv * w4[0];
      acc[q * 4 + 1] += xv * w4[1];
      acc[q * 4 + 2] += xv * w4[2];
      acc[q * 4 + 3] += xv * w4[3];
    }
  }
#pragma unroll
  for (int off = 32; off >= 1; off >>= 1) {
#pragma unroll
    for (int e = 0; e < NE; ++e) acc[e] += __shfl_xor(acc[e], off, 64);
  }
  if (lane == 0) {
    float m = acc[0];
#pragma unroll
    for (int e = 1; e < NE; ++e) m = fmaxf(m, acc[e]);
    unsigned used = 0;
    int idx[TOPK];
    float wv[TOPK];
    float wsum = 0.f;
    for (int k = 0; k < TOPK; ++k) {
      int best = 0;
      float bv = -1e30f;
      for (int e = 0; e < NE; ++e) {
        if (!((used >> e) & 1u) && acc[e] > bv) { bv = acc[e]; best = e; }
      }
      used |= 1u << best;
      float w = expf(bv - m);
      idx[k] = best;
      wv[k] = w;
      wsum += w;
    }
    const float inv = 1.f / wsum;
    for (int k = 0; k < TOPK; ++k) {
      expert_of[n * TOPK + k] = idx[k];
      weight_of[n * TOPK + k] = wv[k] * inv;
      atomicAdd(&counts[idx[k]], 1);
    }
  }
}

// ---------------- scan + dense (expert, m0) worklist ----------------
__global__ void k_scan(const int* __restrict__ counts, int* __restrict__ offsets,
                       int* __restrict__ wl_e, int* __restrict__ wl_m,
                       int* __restrict__ wl_n) {
  int s = 0, t = 0;
  for (int e = 0; e < NE; ++e) {
    offsets[e] = s;
    const int c = counts[e];
    for (int m0 = 0; m0 < c; m0 += 128) {
      wl_e[t] = e;
      wl_m[t] = m0;
      ++t;
    }
    s += c;
  }
  offsets[NE] = s;
  *wl_n = t;
}

// ---------------- deterministic stable scatter (1 wave per expert) ----------------
__global__ __launch_bounds__(64) void k_scatter(const int* __restrict__ expert_of,
                                                const float* __restrict__ weight_of,
                                                const int* __restrict__ offsets,
                                                int* __restrict__ slot_token,
                                                float* __restrict__ slot_w) {
  const int e = blockIdx.x;
  const int lane = threadIdx.x;
  int cnt = offsets[e];
  for (int a0 = 0; a0 < NT * TOPK; a0 += 64) {
    const int a = a0 + lane;
    const bool m = (expert_of[a] == e);
    const unsigned long long bal = __ballot(m);
    if (m) {
      const int pos = cnt + __popcll(bal & ((1ull << lane) - 1ull));
      slot_token[pos] = a >> 2;
      slot_w[pos] = weight_of[a];
    }
    cnt += __popcll(bal);
  }
}

// ---------------- X f32 -> bf16 ----------------
__global__ __launch_bounds__(256) void k_xconv(const float* __restrict__ X,
                                               unsigned short* __restrict__ Xb) {
  const int i = blockIdx.x * 256 + threadIdx.x;
  const f32x4 v = ((const f32x4*)X)[i];
  u32x2 t = {pack2(f2bf(v[0]), f2bf(v[1])), pack2(f2bf(v[2]), f2bf(v[3]))};
  ((u32x2*)Xb)[i] = t;
}

// ---------------- W f32 [E][K][N] -> bf16 [E][N][K] (transpose+convert) ----------------
__global__ __launch_bounds__(256) void k_wconv(const float* __restrict__ W,
                                               unsigned short* __restrict__ WT,
                                               int K, int N) {
  const int e = blockIdx.z;
  const int k0 = blockIdx.x * 64;
  const int n0 = blockIdx.y * 64;
  __shared__ float T[64][65];
  const float* src = W + ((size_t)e * K + k0) * N + n0;
  const int t = threadIdx.x;
#pragma unroll
  for (int p = 0; p < 4; ++p) {
    const int q = p * 256 + t;
    const int r = q >> 4, c4 = q & 15;
    f32x4 v = *(const f32x4*)(src + (size_t)r * N + c4 * 4);
    T[r][c4 * 4 + 0] = v[0];
    T[r][c4 * 4 + 1] = v[1];
    T[r][c4 * 4 + 2] = v[2];
    T[r][c4 * 4 + 3] = v[3];
  }
  __syncthreads();
  unsigned short* dst = WT + ((size_t)e * N + n0) * K + k0;
#pragma unroll
  for (int p = 0; p < 2; ++p) {
    const int ch = p * 256 + t;
    const int n = ch >> 3, kc = ch & 7;
    __attribute__((aligned(16))) unsigned short tmp[8];
#pragma unroll
    for (int j = 0; j < 8; ++j) tmp[j] = f2bf(T[kc * 8 + j][n]);
    *(u32x4*)(dst + (size_t)n * K + kc * 8) = *(const u32x4*)tmp;
  }
}

// ---------------- GEMM1: X[sel] @ WguT^T -> silu(g)*u*w -> Y (bf16) ----------------
__global__ __launch_bounds__(256) void k_gemm1(const unsigned short* __restrict__ Xb,
                                               const unsigned short* __restrict__ WguT,
                                               const int* __restrict__ slot_token,
                                               const float* __restrict__ slot_w,
                                               const int* __restrict__ offsets,
                                               const int* __restrict__ wl_e,
                                               const int* __restrict__ wl_m,
                                               const int* __restrict__ wl_n,
                                               unsigned short* __restrict__ Y) {
  const int tile = blockIdx.x;
  if (tile >= *wl_n) return;
  const int e = wl_e[tile];
  const int m0 = wl_m[tile];
  const int base = offsets[e];
  const int ne = offsets[e + 1] - base;
  const int n0 = blockIdx.y * 64;
  const int tid = threadIdx.x;
  const int lane = tid & 63, w = tid >> 6;
  const int wr = w >> 1, wc = w & 1;
  const int fr = lane & 15, fo = lane >> 4;
  const int lr = lane >> 3, lk = lane & 7;

  __shared__ __attribute__((aligned(16))) unsigned short As[128 * 64];
  __shared__ __attribute__((aligned(16))) unsigned short Bg[64 * 64];
  __shared__ __attribute__((aligned(16))) unsigned short Bu[64 * 64];

  f32x4 accg[4][2], accu[4][2];
#pragma unroll
  for (int i = 0; i < 4; ++i)
#pragma unroll
    for (int j = 0; j < 2; ++j) {
      f32x4 z = {0.f, 0.f, 0.f, 0.f};
      accg[i][j] = z;
      accu[i][j] = z;
    }

  const unsigned short* asrc[4];
#pragma unroll
  for (int i = 0; i < 4; ++i) {
    const int ra = (w * 4 + i) * 8 + lr;
    const int tok = slot_token[base + min(m0 + ra, ne - 1)];
    asrc[i] = Xb + (size_t)tok * HID + ((lk ^ (ra & 7)) << 3);
  }
  const unsigned short* gsrc[2];
  const unsigned short* usrc[2];
#pragma unroll
  for (int j = 0; j < 2; ++j) {
    const int rb = (w * 2 + j) * 8 + lr;
    gsrc[j] = WguT + ((size_t)e * (2 * INTER) + n0 + rb) * HID + ((lk ^ (rb & 7)) << 3);
    usrc[j] = WguT + ((size_t)e * (2 * INTER) + INTER + n0 + rb) * HID + ((lk ^ (rb & 7)) << 3);
  }

  for (int k0 = 0; k0 < HID; k0 += 64) {
#pragma unroll
    for (int i = 0; i < 4; ++i) gload16(asrc[i] + k0, &As[(w * 4 + i) * 512]);
#pragma unroll
    for (int j = 0; j < 2; ++j) {
      gload16(gsrc[j] + k0, &Bg[(w * 2 + j) * 512]);
      gload16(usrc[j] + k0, &Bu[(w * 2 + j) * 512]);
    }
    __syncthreads();
#pragma unroll
    for (int ks = 0; ks < 2; ++ks) {
      const int c = ks * 4 + fo;
      short8 a[4], bg[2], bu[2];
#pragma unroll
      for (int mi = 0; mi < 4; ++mi) {
        const int row = wr * 64 + mi * 16 + fr;
        a[mi] = *(const short8*)&As[row * 64 + ((c ^ (row & 7)) << 3)];
      }
#pragma unroll
      for (int ni = 0; ni < 2; ++ni) {
        const int row = wc * 32 + ni * 16 + fr;
        const int off = row * 64 + ((c ^ (row & 7)) << 3);
        bg[ni] = *(const short8*)&Bg[off];
        bu[ni] = *(const short8*)&Bu[off];
      }
#pragma unroll
      for (int mi = 0; mi < 4; ++mi)
#pragma unroll
        for (int ni = 0; ni < 2; ++ni) {
          accg[mi][ni] = mfma_bf16(a[mi], bg[ni], accg[mi][ni]);
          accu[mi][ni] = mfma_bf16(a[mi], bu[ni], accu[mi][ni]);
        }
    }
    __syncthreads();
  }

#pragma unroll
  for (int mi = 0; mi < 4; ++mi) {
#pragma unroll
    for (int j = 0; j < 4; ++j) {
      const int gm = m0 + wr * 64 + mi * 16 + fo * 4 + j;
      if (gm < ne) {
        const float wgt = slot_w[base + gm];
        unsigned short* yp = Y + (size_t)(base + gm) * INTER + n0 + wc * 32;
#pragma unroll
        for (int ni = 0; ni < 2; ++ni) {
          const float g = accg[mi][ni][j];
          const float u = accu[mi][ni][j];
          const float yv = (g / (1.0f + __expf(-g))) * u * wgt;
          yp[ni * 16 + fr] = f2bf(yv);
        }
      }
    }
  }
}

// ---------------- GEMM2: Y @ WdT^T -> atomic scatter into out ----------------
__global__ __launch_bounds__(256) void k_gemm2(const unsigned short* __restrict__ Y,
                                               const unsigned short* __restrict__ WdT,
                                               const int* __restrict__ slot_token,
                                               const int* __restrict__ offsets,
                                               const int* __restrict__ wl_e,
                                               const int* __restrict__ wl_m,
                                               const int* __restrict__ wl_n,
                                               float* __restrict__ out) {
  const int tile = blockIdx.x;
  if (tile >= *wl_n) return;
  const int e = wl_e[tile];
  const int m0 = wl_m[tile];
  const int base = offsets[e];
  const int ne = offsets[e + 1] - base;
  const int n0 = blockIdx.y * 128;
  const int tid = threadIdx.x;
  const int lane = tid & 63, w = tid >> 6;
  const int wr = w >> 1, wc = w & 1;
  const int fr = lane & 15, fo = lane >> 4;
  const int lr = lane >> 3, lk = lane & 7;

  __shared__ __attribute__((aligned(16))) unsigned short As[128 * 64];
  __shared__ __attribute__((aligned(16))) unsigned short Bs[128 * 64];

  f32x4 acc[4][4];
#pragma unroll
  for (int i = 0; i < 4; ++i)
#pragma unroll
    for (int j = 0; j < 4; ++j) {
      f32x4 z = {0.f, 0.f, 0.f, 0.f};
      acc[i][j] = z;
    }

  const unsigned short* asrc[4];
  const unsigned short* bsrc[4];
#pragma unroll
  for (int i = 0; i < 4; ++i) {
    const int ra = (w * 4 + i) * 8 + lr;
    const int grow = base + min(m0 + ra, ne - 1);
    asrc[i] = Y + (size_t)grow * INTER + ((lk ^ (ra & 7)) << 3);
    bsrc[i] = WdT + ((size_t)e * HID + n0 + ra) * INTER + ((lk ^ (ra & 7)) << 3);
  }

  for (int k0 = 0; k0 < INTER; k0 += 64) {
#pragma unroll
    for (int i = 0; i < 4; ++i) {
      gload16(asrc[i] + k0, &As[(w * 4 + i) * 512]);
      gload16(bsrc[i] + k0, &Bs[(w * 4 + i) * 512]);
    }
    __syncthreads();
#pragma unroll
    for (int ks = 0; ks < 2; ++ks) {
      const int c = ks * 4 + fo;
      short8 a[4], b[4];
#pragma unroll
      for (int mi = 0; mi < 4; ++mi) {
        const int row = wr * 64 + mi * 16 + fr;
        a[mi] = *(const short8*)&As[row * 64 + ((c ^ (row & 7)) << 3)];
      }
#pragma unroll
      for (int ni = 0; ni < 4; ++ni) {
        const int row = wc * 64 + ni * 16 + fr;
        b[ni] = *(const short8*)&Bs[row * 64 + ((c ^ (row & 7)) << 3)];
      }
#pragma unroll
      for (int mi = 0; mi < 4; ++mi)
#pragma unroll
        for (int ni = 0; ni < 4; ++ni) acc[mi][ni] = mfma_bf16(a[mi], b[ni], acc[mi][ni]);
    }
    __syncthreads();
  }

#pragma unroll
  for (int mi = 0; mi < 4; ++mi) {
#pragma unroll
    for (int j = 0; j < 4; ++j) {
      const int gm = m0 + wr * 64 + mi * 16 + fo * 4 + j;
      if (gm < ne) {
        const int tok = slot_token[base + gm];
        float* op = out + (size_t)tok * HID + n0 + wc * 64;
#pragma unroll
        for (int ni = 0; ni < 4; ++ni) atomicAdd(&op[ni * 16 + fr], acc[mi][ni][j]);
      }
    }
  }
}

extern "C" void kernel_launch(void* const* d_in, const int* in_sizes, int n_in,
                              void* d_out, int out_size, void* d_ws, size_t ws_size,
                              hipStream_t stream) {
  (void)in_sizes; (void)n_in; (void)ws_size;
  const float* X = (const float*)d_in[0];
  const float* Wg = (const float*)d_in[1];
  const float* Wgu = (const float*)d_in[2];
  const float* Wd = (const float*)d_in[3];
  float* out = (float*)d_out;

  char* ws = (char*)d_ws;
  int* counts = (int*)(ws + 0);
  int* offsets = (int*)(ws + 256);
  int* wl_n = (int*)(ws + 512);
  int* wl_e = (int*)(ws + 1024);
  int* wl_m = (int*)(ws + 1536);
  int* expert_of = (int*)(ws + 2048);
  float* weight_of = (float*)(ws + 2048 + 32768);
  int* slot_token = (int*)(ws + 2048 + 2 * 32768);
  float* slot_w = (float*)(ws + 2048 + 3 * 32768);
  unsigned short* Xb = (unsigned short*)(ws + 133120);
  unsigned short* Yb = (unsigned short*)(ws + 8521728);
  unsigned short* WguT = (unsigned short*)(ws + 21104640);
  unsigned short* WdT = (unsigned short*)(ws + 222431232);

  hipMemsetAsync(counts, 0, 128, stream);
  hipMemsetAsync(d_out, 0, (size_t)out_size * sizeof(float), stream);

  k_router<<<NT, 64, 0, stream>>>(X, Wg, expert_of, weight_of, counts);
  k_scan<<<1, 1, 0, stream>>>(counts, offsets, wl_e, wl_m, wl_n);
  k_scatter<<<NE, 64, 0, stream>>>(expert_of, weight_of, offsets, slot_token, slot_w);
  k_xconv<<<(NT * HID / 4) / 256, 256, 0, stream>>>(X, Xb);
  k_wconv<<<dim3(HID / 64, (2 * INTER) / 64, NE), 256, 0, stream>>>(Wgu, WguT, HID, 2 * INTER);
  k_wconv<<<dim3(INTER / 64, HID / 64, NE), 256, 0, stream>>>(Wd, WdT, INTER, HID);
  k_gemm1<<<dim3(MAXTILE, INTER / 64), 256, 0, stream>>>(Xb, WguT, slot_token, slot_w,
                                                         offsets, wl_e, wl_m, wl_n, Yb);
  k_gemm2<<<dim3(MAXTILE, HID / 128), 256, 0, stream>>>(Yb, WdT, slot_token, offsets,
                                                        wl_e, wl_m, wl_n, out);
}

// Round 4
// 481.767 us; speedup vs baseline: 3.8852x; 1.2309x over previous
//
#include <hip/hip_runtime.h>
#include <hip/hip_bf16.h>

#define NE 32
#define TOPK 4
#define HID 2048
#define INTER 768
#define NT 2048
#define MAXTILE 64

typedef float f32x4 __attribute__((ext_vector_type(4)));
typedef float f32x2 __attribute__((ext_vector_type(2)));
typedef unsigned int u32x4 __attribute__((ext_vector_type(4)));
typedef unsigned int u32x2 __attribute__((ext_vector_type(2)));
typedef short short8 __attribute__((ext_vector_type(8)));
typedef __bf16 bf16x8 __attribute__((ext_vector_type(8)));

__device__ inline unsigned short f2bf(float f) {
  unsigned u = __builtin_bit_cast(unsigned, f);
  u += 0x7fffu + ((u >> 16) & 1u);
  return (unsigned short)(u >> 16);
}
__device__ inline unsigned pack2(unsigned short a, unsigned short b) {
  return (unsigned)a | ((unsigned)b << 16);
}
__device__ inline f32x4 mfma_bf16(short8 a, short8 b, f32x4 c) {
  return __builtin_amdgcn_mfma_f32_16x16x32_bf16(
      __builtin_bit_cast(bf16x8, a), __builtin_bit_cast(bf16x8, b), c, 0, 0, 0);
}
__device__ inline void gload16(const void* g, void* l) {
  __builtin_amdgcn_global_load_lds(
      (const __attribute__((address_space(1))) void*)g,
      (__attribute__((address_space(3))) void*)l, 16, 0, 0);
}

// ---------------- router: 1 wave per token ----------------
__global__ __launch_bounds__(64) void k_router(const float* __restrict__ X,
                                               const float* __restrict__ Wg,
                                               int* __restrict__ expert_of,
                                               float* __restrict__ weight_of,
                                               int* __restrict__ counts) {
  const int n = blockIdx.x;
  const int lane = threadIdx.x;
  const float* x = X + (size_t)n * HID;
  float acc[NE];
#pragma unroll
  for (int e = 0; e < NE; ++e) acc[e] = 0.f;
  for (int h = lane; h < HID; h += 64) {
    const float xv = x[h];
    const f32x4* wr = (const f32x4*)(Wg + (size_t)h * NE);
#pragma unroll
    for (int q = 0; q < NE / 4; ++q) {
      f32x4 w4 = wr[q];
      acc[q * 4 + 0] += xv * w4[0];
      acc[q * 4 + 1] += xv * w4[1];
      acc[q * 4 + 2] += xv * w4[2];
      acc[q * 4 + 3] += xv * w4[3];
    }
  }
#pragma unroll
  for (int off = 32; off >= 1; off >>= 1) {
#pragma unroll
    for (int e = 0; e < NE; ++e) acc[e] += __shfl_xor(acc[e], off, 64);
  }
  if (lane == 0) {
    float m = acc[0];
#pragma unroll
    for (int e = 1; e < NE; ++e) m = fmaxf(m, acc[e]);
    unsigned used = 0;
    int idx[TOPK];
    float wv[TOPK];
    float wsum = 0.f;
    for (int k = 0; k < TOPK; ++k) {
      int best = 0;
      float bv = -1e30f;
      for (int e = 0; e < NE; ++e) {
        if (!((used >> e) & 1u) && acc[e] > bv) { bv = acc[e]; best = e; }
      }
      used |= 1u << best;
      float w = expf(bv - m);
      idx[k] = best;
      wv[k] = w;
      wsum += w;
    }
    const float inv = 1.f / wsum;
    for (int k = 0; k < TOPK; ++k) {
      expert_of[n * TOPK + k] = idx[k];
      weight_of[n * TOPK + k] = wv[k] * inv;
      atomicAdd(&counts[idx[k]], 1);
    }
  }
}

// ---------------- scan + dense (expert, m0) worklist, m-tile = 256 ----------------
__global__ void k_scan(const int* __restrict__ counts, int* __restrict__ offsets,
                       int* __restrict__ wl_e, int* __restrict__ wl_m,
                       int* __restrict__ wl_n) {
  int s = 0, t = 0;
  for (int e = 0; e < NE; ++e) {
    offsets[e] = s;
    const int c = counts[e];
    for (int m0 = 0; m0 < c; m0 += 256) {
      wl_e[t] = e;
      wl_m[t] = m0;
      ++t;
    }
    s += c;
  }
  offsets[NE] = s;
  *wl_n = t;
}

// ---------------- deterministic stable scatter (1 wave per expert) ----------------
__global__ __launch_bounds__(64) void k_scatter(const int* __restrict__ expert_of,
                                                const float* __restrict__ weight_of,
                                                const int* __restrict__ offsets,
                                                int* __restrict__ slot_token,
                                                float* __restrict__ slot_w) {
  const int e = blockIdx.x;
  const int lane = threadIdx.x;
  int cnt = offsets[e];
  for (int a0 = 0; a0 < NT * TOPK; a0 += 64) {
    const int a = a0 + lane;
    const bool m = (expert_of[a] == e);
    const unsigned long long bal = __ballot(m);
    if (m) {
      const int pos = cnt + __popcll(bal & ((1ull << lane) - 1ull));
      slot_token[pos] = a >> 2;
      slot_w[pos] = weight_of[a];
    }
    cnt += __popcll(bal);
  }
}

// ---------------- X f32 -> bf16 ----------------
__global__ __launch_bounds__(256) void k_xconv(const float* __restrict__ X,
                                               unsigned short* __restrict__ Xb) {
  const int i = blockIdx.x * 256 + threadIdx.x;
  const f32x4 v = ((const f32x4*)X)[i];
  u32x2 t = {pack2(f2bf(v[0]), f2bf(v[1])), pack2(f2bf(v[2]), f2bf(v[3]))};
  ((u32x2*)Xb)[i] = t;
}

// ---------------- GEMM1: X[sel] @ Wgu -> silu(g)*u*w -> Y (bf16) ----------------
// M=256, N=64(gate)+64(up), BK=64, 512 threads (8 waves, 4m x 2n).
// A: bf16 via global_load_lds (pre-swizzled src). B: f32 reg-staged -> bf16 swizzled LDS.
__global__ __launch_bounds__(512) void k_gemm1(const unsigned short* __restrict__ Xb,
                                               const float* __restrict__ Wgu,
                                               const int* __restrict__ slot_token,
                                               const float* __restrict__ slot_w,
                                               const int* __restrict__ offsets,
                                               const int* __restrict__ wl_e,
                                               const int* __restrict__ wl_m,
                                               const int* __restrict__ wl_n,
                                               unsigned short* __restrict__ Y) {
  const int tile = blockIdx.x;
  if (tile >= *wl_n) return;
  const int e = wl_e[tile];
  const int m0 = wl_m[tile];
  const int base = offsets[e];
  const int ne = offsets[e + 1] - base;
  const int n0 = blockIdx.y * 64;
  const int tid = threadIdx.x;
  const int lane = tid & 63, w = tid >> 6;
  const int wm = w >> 1, wn = w & 1;
  const int fr = lane & 15, fo = lane >> 4;
  const int lr = lane >> 3, lk = lane & 7;

  __shared__ __attribute__((aligned(16))) unsigned short As[256 * 64];  // 32 KB
  __shared__ __attribute__((aligned(16))) unsigned short Bg[64 * 64];   // 8 KB
  __shared__ __attribute__((aligned(16))) unsigned short Bu[64 * 64];   // 8 KB

  f32x4 accg[4][2], accu[4][2];
#pragma unroll
  for (int i = 0; i < 4; ++i)
#pragma unroll
    for (int j = 0; j < 2; ++j) {
      f32x4 z = {0.f, 0.f, 0.f, 0.f};
      accg[i][j] = z;
      accu[i][j] = z;
    }

  // A sources: 4 issues/thread, wave w issue i covers rows (w*4+i)*8 .. +7
  const unsigned short* asrc[4];
#pragma unroll
  for (int i = 0; i < 4; ++i) {
    const int ra = (w * 4 + i) * 8 + lr;
    const int tok = slot_token[base + min(m0 + ra, ne - 1)];
    asrc[i] = Xb + (size_t)tok * HID + ((lk ^ (ra & 7)) << 3);
  }

  // B staging map: threads 0..255 gate, 256..511 up; np = pair of n-rows, kg = k-chunk
  const int np = tid & 31, kg = (tid >> 5) & 7, rg = tid >> 8;
  const float* bsrc = Wgu + (size_t)e * HID * (2 * INTER) + (size_t)(kg * 8) * (2 * INTER) +
                      rg * INTER + n0 + 2 * np;
  unsigned short* Bd = rg ? Bu : Bg;
  const int n_a = 2 * np, n_b = 2 * np + 1;
  const int wofa = n_a * 64 + ((kg ^ (n_a & 7)) << 3);
  const int wofb = n_b * 64 + ((kg ^ (n_b & 7)) << 3);

  for (int k0 = 0; k0 < HID; k0 += 64) {
#pragma unroll
    for (int i = 0; i < 4; ++i) gload16(asrc[i] + k0, &As[(w * 4 + i) * 512]);
    const float* bp = bsrc + (size_t)k0 * (2 * INTER);
    f32x2 bv[8];
#pragma unroll
    for (int j = 0; j < 8; ++j) bv[j] = *(const f32x2*)(bp + (size_t)j * (2 * INTER));
    u32x4 ta = {pack2(f2bf(bv[0][0]), f2bf(bv[1][0])), pack2(f2bf(bv[2][0]), f2bf(bv[3][0])),
                pack2(f2bf(bv[4][0]), f2bf(bv[5][0])), pack2(f2bf(bv[6][0]), f2bf(bv[7][0]))};
    u32x4 tb = {pack2(f2bf(bv[0][1]), f2bf(bv[1][1])), pack2(f2bf(bv[2][1]), f2bf(bv[3][1])),
                pack2(f2bf(bv[4][1]), f2bf(bv[5][1])), pack2(f2bf(bv[6][1]), f2bf(bv[7][1]))};
    *(u32x4*)&Bd[wofa] = ta;
    *(u32x4*)&Bd[wofb] = tb;
    __syncthreads();
#pragma unroll
    for (int ks = 0; ks < 2; ++ks) {
      const int c = ks * 4 + fo;
      short8 a[4], bg[2], bu[2];
#pragma unroll
      for (int mi = 0; mi < 4; ++mi) {
        const int row = wm * 64 + mi * 16 + fr;
        a[mi] = *(const short8*)&As[row * 64 + ((c ^ (row & 7)) << 3)];
      }
#pragma unroll
      for (int ni = 0; ni < 2; ++ni) {
        const int row = wn * 32 + ni * 16 + fr;
        const int off = row * 64 + ((c ^ (row & 7)) << 3);
        bg[ni] = *(const short8*)&Bg[off];
        bu[ni] = *(const short8*)&Bu[off];
      }
#pragma unroll
      for (int mi = 0; mi < 4; ++mi)
#pragma unroll
        for (int ni = 0; ni < 2; ++ni) {
          accg[mi][ni] = mfma_bf16(a[mi], bg[ni], accg[mi][ni]);
          accu[mi][ni] = mfma_bf16(a[mi], bu[ni], accu[mi][ni]);
        }
    }
    __syncthreads();
  }

#pragma unroll
  for (int mi = 0; mi < 4; ++mi) {
#pragma unroll
    for (int j = 0; j < 4; ++j) {
      const int gm = m0 + wm * 64 + mi * 16 + fo * 4 + j;
      if (gm < ne) {
        const float wgt = slot_w[base + gm];
        unsigned short* yp = Y + (size_t)(base + gm) * INTER + n0 + wn * 32;
#pragma unroll
        for (int ni = 0; ni < 2; ++ni) {
          const float g = accg[mi][ni][j];
          const float u = accu[mi][ni][j];
          const float yv = (g / (1.0f + __expf(-g))) * u * wgt;
          yp[ni * 16 + fr] = f2bf(yv);
        }
      }
    }
  }
}

// ---------------- GEMM2: Y @ Wd -> atomic scatter into out ----------------
// M=256, N=128, BK=64, K=INTER, 512 threads (8 waves, 4m x 2n).
__global__ __launch_bounds__(512) void k_gemm2(const unsigned short* __restrict__ Y,
                                               const float* __restrict__ Wd,
                                               const int* __restrict__ slot_token,
                                               const int* __restrict__ offsets,
                                               const int* __restrict__ wl_e,
                                               const int* __restrict__ wl_m,
                                               const int* __restrict__ wl_n,
                                               float* __restrict__ out) {
  const int tile = blockIdx.x;
  if (tile >= *wl_n) return;
  const int e = wl_e[tile];
  const int m0 = wl_m[tile];
  const int base = offsets[e];
  const int ne = offsets[e + 1] - base;
  const int n0 = blockIdx.y * 128;
  const int tid = threadIdx.x;
  const int lane = tid & 63, w = tid >> 6;
  const int wm = w >> 1, wn = w & 1;
  const int fr = lane & 15, fo = lane >> 4;
  const int lr = lane >> 3, lk = lane & 7;

  __shared__ __attribute__((aligned(16))) unsigned short As[256 * 64];  // 32 KB
  __shared__ __attribute__((aligned(16))) unsigned short Bs[128 * 64];  // 16 KB

  f32x4 acc[4][4];
#pragma unroll
  for (int i = 0; i < 4; ++i)
#pragma unroll
    for (int j = 0; j < 4; ++j) {
      f32x4 z = {0.f, 0.f, 0.f, 0.f};
      acc[i][j] = z;
    }

  const unsigned short* asrc[4];
#pragma unroll
  for (int i = 0; i < 4; ++i) {
    const int ra = (w * 4 + i) * 8 + lr;
    const int grow = base + min(m0 + ra, ne - 1);
    asrc[i] = Y + (size_t)grow * INTER + ((lk ^ (ra & 7)) << 3);
  }

  // B staging: np = lane (pair of n-rows), kg = wave (k-chunk)
  const int np = tid & 63, kg = tid >> 6;
  const float* bsrc = Wd + (size_t)e * INTER * HID + (size_t)(kg * 8) * HID + n0 + 2 * np;
  const int n_a = 2 * np, n_b = 2 * np + 1;
  const int wofa = n_a * 64 + ((kg ^ (n_a & 7)) << 3);
  const int wofb = n_b * 64 + ((kg ^ (n_b & 7)) << 3);

  for (int k0 = 0; k0 < INTER; k0 += 64) {
#pragma unroll
    for (int i = 0; i < 4; ++i) gload16(asrc[i] + k0, &As[(w * 4 + i) * 512]);
    const float* bp = bsrc + (size_t)k0 * HID;
    f32x2 bv[8];
#pragma unroll
    for (int j = 0; j < 8; ++j) bv[j] = *(const f32x2*)(bp + (size_t)j * HID);
    u32x4 ta = {pack2(f2bf(bv[0][0]), f2bf(bv[1][0])), pack2(f2bf(bv[2][0]), f2bf(bv[3][0])),
                pack2(f2bf(bv[4][0]), f2bf(bv[5][0])), pack2(f2bf(bv[6][0]), f2bf(bv[7][0]))};
    u32x4 tb = {pack2(f2bf(bv[0][1]), f2bf(bv[1][1])), pack2(f2bf(bv[2][1]), f2bf(bv[3][1])),
                pack2(f2bf(bv[4][1]), f2bf(bv[5][1])), pack2(f2bf(bv[6][1]), f2bf(bv[7][1]))};
    *(u32x4*)&Bs[wofa] = ta;
    *(u32x4*)&Bs[wofb] = tb;
    __syncthreads();
#pragma unroll
    for (int ks = 0; ks < 2; ++ks) {
      const int c = ks * 4 + fo;
      short8 a[4], b[4];
#pragma unroll
      for (int mi = 0; mi < 4; ++mi) {
        const int row = wm * 64 + mi * 16 + fr;
        a[mi] = *(const short8*)&As[row * 64 + ((c ^ (row & 7)) << 3)];
      }
#pragma unroll
      for (int ni = 0; ni < 4; ++ni) {
        const int row = wn * 64 + ni * 16 + fr;
        b[ni] = *(const short8*)&Bs[row * 64 + ((c ^ (row & 7)) << 3)];
      }
#pragma unroll
      for (int mi = 0; mi < 4; ++mi)
#pragma unroll
        for (int ni = 0; ni < 4; ++ni) acc[mi][ni] = mfma_bf16(a[mi], b[ni], acc[mi][ni]);
    }
    __syncthreads();
  }

#pragma unroll
  for (int mi = 0; mi < 4; ++mi) {
#pragma unroll
    for (int j = 0; j < 4; ++j) {
      const int gm = m0 + wm * 64 + mi * 16 + fo * 4 + j;
      if (gm < ne) {
        const int tok = slot_token[base + gm];
        float* op = out + (size_t)tok * HID + n0 + wn * 64;
#pragma unroll
        for (int ni = 0; ni < 4; ++ni) atomicAdd(&op[ni * 16 + fr], acc[mi][ni][j]);
      }
    }
  }
}

extern "C" void kernel_launch(void* const* d_in, const int* in_sizes, int n_in,
                              void* d_out, int out_size, void* d_ws, size_t ws_size,
                              hipStream_t stream) {
  (void)in_sizes; (void)n_in; (void)ws_size;
  const float* X = (const float*)d_in[0];
  const float* Wg = (const float*)d_in[1];
  const float* Wgu = (const float*)d_in[2];
  const float* Wd = (const float*)d_in[3];
  float* out = (float*)d_out;

  char* ws = (char*)d_ws;
  int* counts = (int*)(ws + 0);
  int* offsets = (int*)(ws + 256);
  int* wl_n = (int*)(ws + 512);
  int* wl_e = (int*)(ws + 1024);
  int* wl_m = (int*)(ws + 1536);
  int* expert_of = (int*)(ws + 2048);
  float* weight_of = (float*)(ws + 2048 + 32768);
  int* slot_token = (int*)(ws + 2048 + 2 * 32768);
  float* slot_w = (float*)(ws + 2048 + 3 * 32768);
  unsigned short* Xb = (unsigned short*)(ws + 133120);   // 8 MB
  unsigned short* Yb = (unsigned short*)(ws + 8521728);  // 12.6 MB

  hipMemsetAsync(counts, 0, 128, stream);
  hipMemsetAsync(d_out, 0, (size_t)out_size * sizeof(float), stream);

  k_router<<<NT, 64, 0, stream>>>(X, Wg, expert_of, weight_of, counts);
  k_scan<<<1, 1, 0, stream>>>(counts, offsets, wl_e, wl_m, wl_n);
  k_scatter<<<NE, 64, 0, stream>>>(expert_of, weight_of, offsets, slot_token, slot_w);
  k_xconv<<<(NT * HID / 4) / 256, 256, 0, stream>>>(X, Xb);
  k_gemm1<<<dim3(MAXTILE, INTER / 64), 512, 0, stream>>>(Xb, Wgu, slot_token, slot_w,
                                                         offsets, wl_e, wl_m, wl_n, Yb);
  k_gemm2<<<dim3(MAXTILE, HID / 128), 512, 0, stream>>>(Yb, Wd, slot_token, offsets,
                                                        wl_e, wl_m, wl_n, out);
}